// Round 7
// baseline (306.844 us; speedup 1.0000x reference)
//
#include <hip/hip_runtime.h>
#include <hip/hip_fp16.h>

namespace {

constexpr int H = 1024, W = 1024, NB = 4;
constexpr int SH = 128, SW = 128;
constexpr float LAM = 0.24f;
constexpr float KK = 0.03f * 0.03f;
constexpr float DEPS_V = 0.1f;
constexpr float FFT_SCALE = 1.0f / (1024.0f * 1024.0f);  // ortho fwd+inv combined
// Processed (masked) columns: |x(k2)| <= 0.5  <=>  k2 in [256, 768). Margin ~1.5e-3 >> fp err.
constexpr int COL_LO = 256, NCOL = 512;

__device__ __forceinline__ float2 cadd(float2 a, float2 b) { return make_float2(a.x + b.x, a.y + b.y); }
__device__ __forceinline__ float2 csub(float2 a, float2 b) { return make_float2(a.x - b.x, a.y - b.y); }
__device__ __forceinline__ float2 cmul(float2 a, float2 b) {
  return make_float2(a.x * b.x - a.y * b.y, a.x * b.y + a.y * b.x);
}
__device__ __forceinline__ int phys2(int e) { return e + (e >> 4); }

__device__ __forceinline__ float shift_from_bits(const unsigned* minp) {
  float mn = __uint_as_float(minp[0]);
  return (mn <= DEPS_V) ? DEPS_V : 0.0f;
}

// ---------------- min(source) via device-scope atomicMin on uint bits ----------------
// source >= 0 -> uint order == float order. ws poison 0xAAAAAAAA > any positive-float
// bits, so the poisoned word is a valid "+inf"-like init (zeroed ws also safe: gives
// min 0 -> shift 0.1, identical to true result for uniform[0,1) source).
__global__ void k_shift_min(const float* __restrict__ src, unsigned* __restrict__ minp) {
  int t = threadIdx.x;
  int b0 = blockIdx.x * 1024;
  float m = fminf(fminf(src[b0 + t], src[b0 + t + 256]),
                  fminf(src[b0 + t + 512], src[b0 + t + 768]));
  for (int o = 32; o > 0; o >>= 1) m = fminf(m, __shfl_xor(m, o));
  __shared__ float sm[4];
  if ((t & 63) == 0) sm[t >> 6] = m;
  __syncthreads();
  if (t == 0) {
    float mm = fminf(fminf(sm[0], sm[1]), fminf(sm[2], sm[3]));
    atomicMin(minp, __float_as_uint(mm));
  }
}

// ---------------- Stockham radix-4 1024-pt FFT (natural in -> natural out) ----------------
template <int NS, bool INV>
__device__ __forceinline__ void r4_butterfly(float2 v[4], int j, float2 r[4]) {
  if (NS > 1) {
    int p = j & (NS - 1);
    float sn, cs;
    sincospif((INV ? 1.0f : -1.0f) * (float)p * (1.0f / (float)(2 * NS)), &sn, &cs);
    float2 w1 = make_float2(cs, sn);
    float2 w2 = cmul(w1, w1);
    float2 w3 = cmul(w2, w1);
    v[1] = cmul(v[1], w1);
    v[2] = cmul(v[2], w2);
    v[3] = cmul(v[3], w3);
  }
  float2 a0 = cadd(v[0], v[2]), a2 = csub(v[0], v[2]);
  float2 a1 = cadd(v[1], v[3]), a3 = csub(v[1], v[3]);
  a3 = INV ? make_float2(-a3.y, a3.x) : make_float2(a3.y, -a3.x);
  r[0] = cadd(a0, a1);
  r[2] = csub(a0, a1);
  r[1] = cadd(a2, a3);
  r[3] = csub(a2, a3);
}

template <int NS, bool INV>
__device__ __forceinline__ void r4_stage_lds(float2 v[4], float2* dst, int j) {
  float2 r[4];
  r4_butterfly<NS, INV>(v, j, r);
  int p = j & (NS - 1);
  int base = ((j - p) << 2) + p;
#pragma unroll
  for (int k = 0; k < 4; ++k) dst[phys2(base + k * NS)] = r[k];
}

__device__ __forceinline__ void lds_load4(const float2* src, float2 v[4], int j) {
#pragma unroll
  for (int k = 0; k < 4; ++k) v[k] = src[phys2(j + k * 256)];
}

template <bool INV>
__device__ void fft1024(float2 v[4], float2* b0, float2* b1, int j) {
  r4_stage_lds<1, INV>(v, b0, j);
  __syncthreads();
  lds_load4(b0, v, j);
  r4_stage_lds<4, INV>(v, b1, j);
  __syncthreads();
  lds_load4(b1, v, j);
  r4_stage_lds<16, INV>(v, b0, j);
  __syncthreads();
  lds_load4(b0, v, j);
  r4_stage_lds<64, INV>(v, b1, j);
  __syncthreads();
  lds_load4(b1, v, j);
  float2 r[4];
  r4_butterfly<256, INV>(v, j, r);
#pragma unroll
  for (int k = 0; k < 4; ++k) v[k] = r[k];
}

// ---------------- forward row FFT, 2 real rows packed per complex transform ----------------
__global__ void k_rowfft_fwd(const float* __restrict__ guide, const float* __restrict__ ybic,
                             const unsigned* __restrict__ minp, float2* __restrict__ A) {
  __shared__ float2 b0[1088], b1[1088];
  int b = blockIdx.y, y0 = blockIdx.x * 2, j = threadIdx.x;
  float sh = shift_from_bits(minp);
  const float* g0 = guide + ((size_t)(b * 3 + 0) * H + y0) * W;
  const float* g1 = guide + ((size_t)(b * 3 + 1) * H + y0) * W;
  const float* g2 = guide + ((size_t)(b * 3 + 2) * H + y0) * W;
  const float* yb = ybic + ((size_t)b * H + y0) * W;
  float2 v[4];
#pragma unroll
  for (int k = 0; k < 4; ++k) {
    int x = j + k * 256;
    float s0 = g0[x] + g1[x] + g2[x] + (yb[x] + sh);
    float s1 = g0[x + W] + g1[x + W] + g2[x + W] + (yb[x + W] + sh);
    v[k] = make_float2(s0, s1);
  }
  fft1024<false>(v, b0, b1, j);
#pragma unroll
  for (int k = 0; k < 4; ++k) b0[phys2(j + k * 256)] = v[k];
  __syncthreads();
  float2* o0 = A + ((size_t)b * H + y0) * W;
  float2* o1 = o0 + W;
#pragma unroll
  for (int k = 0; k < 4; ++k) {
    int m = j + k * 256;
    float2 Zm = v[k];
    float2 Zc = b0[phys2((1024 - m) & 1023)];
    o0[m] = make_float2(0.5f * (Zm.x + Zc.x), 0.5f * (Zm.y - Zc.y));
    o1[m] = make_float2(0.5f * (Zm.y + Zc.y), 0.5f * (Zc.x - Zm.x));
  }
}

// ---------------- half-width transposes: only columns [256,768) round-trip ----------------
__global__ void k_transpose_fwd(const float2* __restrict__ A, float2* __restrict__ Bc) {
  __shared__ float2 tile[32][33];
  int b = blockIdx.z;
  int c0 = blockIdx.x * 32, y0 = blockIdx.y * 32;
  const float2* ip = A + (size_t)b * H * W;
  float2* op = Bc + (size_t)b * NCOL * H;
#pragma unroll
  for (int k = 0; k < 4; ++k)
    tile[threadIdx.y + k * 8][threadIdx.x] =
        ip[(size_t)(y0 + threadIdx.y + k * 8) * W + (COL_LO + c0 + threadIdx.x)];
  __syncthreads();
#pragma unroll
  for (int k = 0; k < 4; ++k)
    op[(size_t)(c0 + threadIdx.y + k * 8) * H + (y0 + threadIdx.x)] =
        tile[threadIdx.x][threadIdx.y + k * 8];
}

__global__ void k_transpose_bwd(const float2* __restrict__ Bc, float2* __restrict__ A) {
  __shared__ float2 tile[32][33];
  int b = blockIdx.z;
  int c0 = blockIdx.x * 32, y0 = blockIdx.y * 32;
  const float2* ip = Bc + (size_t)b * NCOL * H;
  float2* op = A + (size_t)b * H * W;
#pragma unroll
  for (int k = 0; k < 4; ++k)
    tile[threadIdx.y + k * 8][threadIdx.x] =
        ip[(size_t)(c0 + threadIdx.y + k * 8) * H + (y0 + threadIdx.x)];
  __syncthreads();
#pragma unroll
  for (int k = 0; k < 4; ++k)
    op[(size_t)(y0 + threadIdx.y + k * 8) * W + (COL_LO + c0 + threadIdx.x)] =
        tile[threadIdx.x][threadIdx.y + k * 8];
}

// ---------------- column FFT + radial mask + inverse column FFT ----------------
__global__ void k_colfft_mask(float2* __restrict__ Bc) {
  __shared__ float2 b0[1088], b1[1088];
  int b = blockIdx.y, r = blockIdx.x, j = threadIdx.x;
  int k2 = COL_LO + r;
  double xj = -1.0 + 2.0 * (double)k2 / 1023.0;
  double xj2 = xj * xj;
  float2* row = Bc + ((size_t)b * NCOL + r) * H;
  float2 v[4];
#pragma unroll
  for (int k = 0; k < 4; ++k) v[k] = row[j + k * 256];
  fft1024<false>(v, b0, b1, j);
#pragma unroll
  for (int k = 0; k < 4; ++k) {
    int i = j + k * 256;
    double yv = -1.0 + 2.0 * (double)i / 1023.0;
    if (xj2 + yv * yv <= 0.25) v[k] = make_float2(0.0f, 0.0f);
  }
  fft1024<true>(v, b0, b1, j);
#pragma unroll
  for (int k = 0; k < 4; ++k) row[j + k * 256] = v[k];
}

// ---------------- inverse row FFT -> er (skipped cols compensated x1024) ----------------
__global__ void k_rowfft_inv(const float2* __restrict__ A, float* __restrict__ er) {
  __shared__ float2 b0[1088], b1[1088];
  int b = blockIdx.y, y = blockIdx.x, j = threadIdx.x;
  const float2* in = A + ((size_t)b * H + y) * W;
  float2 v[4];
#pragma unroll
  for (int k = 0; k < 4; ++k) v[k] = in[j + k * 256];
  v[0].x *= 1024.0f; v[0].y *= 1024.0f;
  v[3].x *= 1024.0f; v[3].y *= 1024.0f;
  fft1024<true>(v, b0, b1, j);
  float* out = er + ((size_t)b * H + y) * W;
#pragma unroll
  for (int k = 0; k < 4; ++k) out[j + k * 256] = v[k].x * FFT_SCALE;
}

// ---------------- Perona-Malik coefficients, packed half2 {cv, ch}, 4 px/thread ----------
__global__ void k_coeffs(const float* __restrict__ guide, const float* __restrict__ ybic,
                         const float* __restrict__ er, __half2* __restrict__ cvh) {
  int b = blockIdx.y, y = blockIdx.x, t = threadIdx.x;
  int x0 = t * 4;
  const float* g = guide + (size_t)b * 3 * H * W;
  const float* yb = ybic + (size_t)b * H * W;
  const float* e = er + (size_t)b * H * W;
  __half2* cp = cvh + (size_t)b * H * W;
  const size_t CH = (size_t)H * W;
  size_t row = (size_t)y * W + x0;
  float4 a0 = *(const float4*)(g + row);
  float4 a1 = *(const float4*)(g + CH + row);
  float4 a2 = *(const float4*)(g + 2 * CH + row);
  float4 a3 = *(const float4*)(yb + row);
  float4 e0 = *(const float4*)(e + row);
  float A0[5] = {a0.x, a0.y, a0.z, a0.w, 0.f};
  float A1[5] = {a1.x, a1.y, a1.z, a1.w, 0.f};
  float A2[5] = {a2.x, a2.y, a2.z, a2.w, 0.f};
  float A3[5] = {a3.x, a3.y, a3.z, a3.w, 0.f};
  float E0[5] = {e0.x, e0.y, e0.z, e0.w, 0.f};
  bool hasR = (x0 + 4 < W);
  if (hasR) {
    A0[4] = g[row + 4]; A1[4] = g[CH + row + 4]; A2[4] = g[2 * CH + row + 4];
    A3[4] = yb[row + 4]; E0[4] = e[row + 4];
  }
  float B0[4], B1[4], B2[4], B3[4], E1[4];
  bool hasD = (y < H - 1);
  if (hasD) {
    float4 q0 = *(const float4*)(g + row + W);
    float4 q1 = *(const float4*)(g + CH + row + W);
    float4 q2 = *(const float4*)(g + 2 * CH + row + W);
    float4 q3 = *(const float4*)(yb + row + W);
    float4 q4 = *(const float4*)(e + row + W);
    B0[0]=q0.x; B0[1]=q0.y; B0[2]=q0.z; B0[3]=q0.w;
    B1[0]=q1.x; B1[1]=q1.y; B1[2]=q1.z; B1[3]=q1.w;
    B2[0]=q2.x; B2[1]=q2.y; B2[2]=q2.z; B2[3]=q2.w;
    B3[0]=q3.x; B3[1]=q3.y; B3[2]=q3.z; B3[3]=q3.w;
    E1[0]=q4.x; E1[1]=q4.y; E1[2]=q4.z; E1[3]=q4.w;
  }
  __half2 outq[4];
#pragma unroll
  for (int i = 0; i < 4; ++i) {
    float cvv = 0.0f;
    if (hasD) {
      float s = fabsf(B0[i] - A0[i]) + fabsf(B1[i] - A1[i]) +
                fabsf(B2[i] - A2[i]) + fabsf(B3[i] - A3[i]);
      s = (s + E1[i]) * 0.25f;
      cvv = 1.0f / (1.0f + (s * s) / KK);
    }
    float chv = 0.0f;
    if (i < 3 || hasR) {
      float s = fabsf(A0[i + 1] - A0[i]) + fabsf(A1[i + 1] - A1[i]) +
                fabsf(A2[i + 1] - A2[i]) + fabsf(A3[i + 1] - A3[i]);
      s = (s + E0[i + 1]) * 0.25f;
      chv = 1.0f / (1.0f + (s * s) / KK);
    }
    outq[i] = __floats2half2_rn(cvv, chv);
  }
  *(float4*)(cp + row) = *(const float4*)outq;
}

// ---------------- helpers: 8-px vector load/store ----------------
__device__ __forceinline__ void load8h(const __half* p, float o[8]) {
  float4 raw = *(const float4*)p;
  const __half2* h = (const __half2*)&raw;
#pragma unroll
  for (int i = 0; i < 4; ++i) {
    float2 f = __half22float2(h[i]);
    o[2 * i] = f.x; o[2 * i + 1] = f.y;
  }
}
__device__ __forceinline__ void load8f(const float* p, float o[8]) {
  float4 a = *(const float4*)p;
  float4 c = *(const float4*)(p + 4);
  o[0]=a.x; o[1]=a.y; o[2]=a.z; o[3]=a.w; o[4]=c.x; o[5]=c.y; o[6]=c.z; o[7]=c.w;
}
__device__ __forceinline__ void store8h(__half* p, const float o[8]) {
  float4 raw;
  __half2* h = (__half2*)&raw;
#pragma unroll
  for (int i = 0; i < 4; ++i) h[i] = __floats2half2_rn(o[2 * i], o[2 * i + 1]);
  *(float4*)p = raw;
}

// ---------------- fused diffuse + 8x8 block-mean ratio, 8 px/thread ----------------
// Block (32,8) -> 256x8 tile; each thread's 8 px span exactly one pool-block column chunk.
// fp16 ping-pong buffers; FIRST reads f32 ybic (+shift); FINAL writes f32 out (*ratio - shift).
template <bool FIRST, bool FINAL>
__global__ void k_diffuse_ratio(const float* __restrict__ inF, const __half* __restrict__ inH,
                                const float* __restrict__ ratio_in,
                                const unsigned* __restrict__ minp,
                                const __half2* __restrict__ cvh, const float* __restrict__ src,
                                const float* __restrict__ mask, float* __restrict__ outF,
                                __half* __restrict__ outH, float* __restrict__ ratio_out) {
  int b = blockIdx.z, tx = threadIdx.x, ty = threadIdx.y;
  int x0 = blockIdx.x * 256 + tx * 8;
  int y = blockIdx.y * 8 + ty;
  float sh = shift_from_bits(minp);
  float addv = FIRST ? sh : 0.0f;
  size_t base = (size_t)b * H * W;
  size_t row = (size_t)y * W + x0;
  bool hasU = (y > 0), hasD = (y < H - 1);
  bool hasL = (x0 > 0), hasR = (x0 + 8 < W);
  int px = x0 >> 3;  // pool x (same for all 8 px)
  float rq = 1.f, rup = 1.f, rdn = 1.f, rlf = 1.f, rrt = 1.f;
  if (!FIRST) {
    const float* rb = ratio_in + (size_t)b * SH * SW;
    int py = y >> 3;
    rq = rb[py * SW + px];
    rup = hasU ? rb[((y - 1) >> 3) * SW + px] : 1.f;
    rdn = hasD ? rb[((y + 1) >> 3) * SW + px] : 1.f;
    rlf = hasL ? rb[py * SW + (px - 1)] : 1.f;
    rrt = hasR ? rb[py * SW + (px + 1)] : 1.f;
  }
  float C[8], U[8] = {0}, D[8] = {0};
  float lf = 0.f, rt = 0.f;
  if (FIRST) {
    const float* I = inF + base;
    load8f(I + row, C);
    if (hasU) load8f(I + row - W, U);
    if (hasD) load8f(I + row + W, D);
    if (hasL) lf = I[row - 1];
    if (hasR) rt = I[row + 8];
  } else {
    const __half* I = inH + base;
    load8h(I + row, C);
    if (hasU) load8h(I + row - W, U);
    if (hasD) load8h(I + row + W, D);
    if (hasL) lf = __half2float(I[row - 1]);
    if (hasR) rt = __half2float(I[row + 8]);
  }
#pragma unroll
  for (int i = 0; i < 8; ++i) {
    C[i] = (C[i] + addv) * rq;
    U[i] = (U[i] + addv) * rup;
    D[i] = (D[i] + addv) * rdn;
  }
  lf = (lf + addv) * rlf;
  rt = (rt + addv) * rrt;
  // coefficients
  const __half2* cp = cvh + base;
  float cvq[8], chq[8], cvu[8] = {0};
  {
    float4 r0 = *(const float4*)(cp + row);
    float4 r1 = *(const float4*)(cp + row + 4);
    const __half2* h0 = (const __half2*)&r0;
    const __half2* h1 = (const __half2*)&r1;
#pragma unroll
    for (int i = 0; i < 4; ++i) {
      float2 f = __half22float2(h0[i]); cvq[i] = f.x; chq[i] = f.y;
      float2 g = __half22float2(h1[i]); cvq[i + 4] = g.x; chq[i + 4] = g.y;
    }
    if (hasU) {
      float4 u0 = *(const float4*)(cp + row - W);
      float4 u1 = *(const float4*)(cp + row - W + 4);
      const __half2* p0 = (const __half2*)&u0;
      const __half2* p1 = (const __half2*)&u1;
#pragma unroll
      for (int i = 0; i < 4; ++i) {
        cvu[i] = __half2float(p0[i].x);
        cvu[i + 4] = __half2float(p1[i].x);
      }
    }
  }
  float chl = hasL ? __half2float(cp[row - 1].y) : 0.f;
  float acc[8];
#pragma unroll
  for (int i = 0; i < 8; ++i) {
    float L = (i == 0) ? lf : C[i - 1];
    float R = (i == 7) ? rt : C[i + 1];
    float cL = (i == 0) ? chl : chq[i - 1];
    float a = C[i];
    if (hasD) a += LAM * cvq[i] * (D[i] - C[i]);
    if (hasU) a -= LAM * cvu[i] * (C[i] - U[i]);
    if (i < 7 || hasR) a += LAM * chq[i] * (R - C[i]);
    if (i > 0 || hasL) a -= LAM * cL * (C[i] - L);
    acc[i] = a;
  }
  // 8x8 block-mean -> ratio (thread's 8 px = one pool column chunk at pool x = blockIdx.x*32+tx)
  __shared__ float sd[8][32];
  __shared__ float rblk[32];
  sd[ty][tx] = acc[0] + acc[1] + acc[2] + acc[3] + acc[4] + acc[5] + acc[6] + acc[7];
  __syncthreads();
  if (ty == 0) {
    float s = 0.f;
#pragma unroll
    for (int r = 0; r < 8; ++r) s += sd[r][tx];
    size_t si = ((size_t)b * SH + blockIdx.y) * SW + (blockIdx.x * 32 + tx);
    float mean = s * (1.0f / 64.0f);
    float rv = (mask[si] < 0.5f) ? 1.0f : (src[si] + sh) / (mean + 1e-8f);
    if (FINAL) rblk[tx] = rv;
    else ratio_out[si] = rv;
  }
  if (FINAL) {
    __syncthreads();
    float rv = rblk[tx];
    float o[8];
#pragma unroll
    for (int i = 0; i < 8; ++i) o[i] = acc[i] * rv - sh;
    float* op = outF + base + row;
    *(float4*)op = make_float4(o[0], o[1], o[2], o[3]);
    *(float4*)(op + 4) = make_float4(o[4], o[5], o[6], o[7]);
  } else {
    store8h(outH + base + row, acc);
  }
}

}  // namespace

extern "C" void kernel_launch(void* const* d_in, const int* in_sizes, int n_in, void* d_out,
                              int out_size, void* d_ws, size_t ws_size, hipStream_t stream) {
  (void)in_sizes; (void)n_in; (void)out_size; (void)ws_size;
  const float* guide = (const float*)d_in[0];
  const float* source = (const float*)d_in[1];
  const float* mask = (const float*)d_in[2];
  const float* ybic = (const float*)d_in[3];
  float* out = (float*)d_out;

  char* ws = (char*)d_ws;
  float2* A = (float2*)ws;                                  // [0,32MB), dead after rowfft_inv
  float2* Bc = (float2*)(ws + (size_t)32 * 1024 * 1024);    // [32,48MB), dead after transpose_bwd
  float* er = (float*)(ws + (size_t)32 * 1024 * 1024);      // overlays Bc
  __half2* cvh = (__half2*)(ws + (size_t)48 * 1024 * 1024); // [48,64MB)
  __half* hA = (__half*)ws;                                 // [0,8MB) overlays dead A
  __half* hB = (__half*)(ws + (size_t)8 * 1024 * 1024);     // [8,16MB)
  unsigned* minp = (unsigned*)(ws + (size_t)64 * 1024 * 1024);
  float* ratioA = (float*)(ws + (size_t)64 * 1024 * 1024 + 4096);
  float* ratioB = ratioA + (size_t)NB * SH * SW;

  k_shift_min<<<64, 256, 0, stream>>>(source, minp);

  k_rowfft_fwd<<<dim3(H / 2, NB), 256, 0, stream>>>(guide, ybic, minp, A);
  dim3 gT(NCOL / 32, H / 32, NB), bT(32, 8);
  k_transpose_fwd<<<gT, bT, 0, stream>>>(A, Bc);
  k_colfft_mask<<<dim3(NCOL, NB), 256, 0, stream>>>(Bc);
  k_transpose_bwd<<<gT, bT, 0, stream>>>(Bc, A);
  k_rowfft_inv<<<dim3(H, NB), 256, 0, stream>>>(A, er);

  k_coeffs<<<dim3(H, NB), 256, 0, stream>>>(guide, ybic, er, cvh);

  dim3 gD(W / 256, H / 8, NB), bD(32, 8);
  // it 0: ybic(f32) -> hA
  k_diffuse_ratio<true, false><<<gD, bD, 0, stream>>>(ybic, nullptr, nullptr, minp, cvh,
                                                      source, mask, nullptr, hA, ratioA);
  // its 1..6: fp16 ping-pong
  k_diffuse_ratio<false, false><<<gD, bD, 0, stream>>>(nullptr, hA, ratioA, minp, cvh,
                                                       source, mask, nullptr, hB, ratioB);
  k_diffuse_ratio<false, false><<<gD, bD, 0, stream>>>(nullptr, hB, ratioB, minp, cvh,
                                                       source, mask, nullptr, hA, ratioA);
  k_diffuse_ratio<false, false><<<gD, bD, 0, stream>>>(nullptr, hA, ratioA, minp, cvh,
                                                       source, mask, nullptr, hB, ratioB);
  k_diffuse_ratio<false, false><<<gD, bD, 0, stream>>>(nullptr, hB, ratioB, minp, cvh,
                                                       source, mask, nullptr, hA, ratioA);
  k_diffuse_ratio<false, false><<<gD, bD, 0, stream>>>(nullptr, hA, ratioA, minp, cvh,
                                                       source, mask, nullptr, hB, ratioB);
  k_diffuse_ratio<false, false><<<gD, bD, 0, stream>>>(nullptr, hB, ratioB, minp, cvh,
                                                       source, mask, nullptr, hA, ratioA);
  // it 7 (FINAL): hA -> out(f32), applies own ratio + subtracts shift
  k_diffuse_ratio<false, true><<<gD, bD, 0, stream>>>(nullptr, hA, ratioA, minp, cvh,
                                                      source, mask, out, nullptr, ratioB);
}